// Round 5
// baseline (271.682 us; speedup 1.0000x reference)
//
#include <hip/hip_runtime.h>
#include <math.h>

#define BLOCK 256
#define EPB   512   // elements per block: 2 per thread (ILP for the latency-bound Jacobi chain)

__device__ __forceinline__ float frcp(float x) { return __builtin_amdgcn_rcpf(x); }
__device__ __forceinline__ float frsq(float x) { return __builtin_amdgcn_rsqf(x); }

// One-sided (Hestenes) Jacobi rotation; squared norms carried analytically.
// de Rijk ordering keeps np >= nq. Math identical to R3 (bit-identical canary).
__device__ __forceinline__ void rot(
    float& x0, float& x1, float& x2, float& np,
    float& y0, float& y1, float& y2, float& nq)
{
    float apq = fmaf(x0, y0, fmaf(x1, y1, x2 * y2));
    float del = np - nq;
    float rho = apq + apq;
    float r   = sqrtf(fmaf(del, del, rho * rho));
    float ch  = fabsf(del) + r;
    float sh  = (del < 0.0f) ? -rho : rho;
    float nn  = fmaf(ch, ch, sh * sh);
    float inv = frsq(nn);
    bool ok = nn > 1e-30f;
    float c = ok ? ch * inv : 1.0f;
    float s = ok ? sh * inv : 0.0f;
    bool sw = del < 0.0f;
    float cf = sw ? -s : c;
    float sf = sw ?  c : s;
    float t;
    t = x0; x0 = fmaf(cf, t, sf * y0); y0 = fmaf(cf, y0, -sf * t);
    t = x1; x1 = fmaf(cf, t, sf * y1); y1 = fmaf(cf, y1, -sf * t);
    t = x2; x2 = fmaf(cf, t, sf * y2); y2 = fmaf(cf, y2, -sf * t);
    float sum = np + nq;
    np = 0.5f * (sum + r);
    nq = fmaxf(0.5f * (sum - r), 0.0f);
}

__global__ __launch_bounds__(BLOCK) void dp_kernel(
    const float* __restrict__ F,
    const float* __restrict__ p_yml,
    const float* __restrict__ p_nu,
    const float* __restrict__ p_fa,
    const float* __restrict__ p_coh,
    float* __restrict__ out,
    int n_elem)
{
    __shared__ float lds[EPB * 9];                 // 18432 B
    const int t_id = threadIdx.x;
    const long long base_f = (long long)blockIdx.x * (EPB * 9);
    const long long nfloats = (long long)n_elem * 9LL;

    // ---- stage in: 1152 float4 per block, coalesced ----
    #pragma unroll
    for (int j = 0; j < 5; ++j) {
        int idx = t_id + j * BLOCK;
        if (idx < (EPB * 9) / 4) {
            long long g4 = base_f / 4 + idx;
            long long gf = g4 * 4;
            if (gf + 3 < nfloats) {
                ((float4*)lds)[idx] = ((const float4*)F)[g4];
            } else {
                #pragma unroll
                for (int k = 0; k < 4; ++k)
                    if (gf + k < nfloats) lds[idx * 4 + k] = F[gf + k];
            }
        }
    }
    __syncthreads();

    const long long e0 = (long long)blockIdx.x * EPB + t_id;
    const long long e1 = e0 + BLOCK;
    const bool valid0 = e0 < n_elem;
    const bool valid1 = e1 < n_elem;
    const int off0 = t_id * 9;
    const int off1 = (t_id + BLOCK) * 9;

    // ---- material params (wave-uniform) ----
    const float yml = p_yml[0];
    const float nu  = p_nu[0];
    const float fa  = p_fa[0];
    const float coh = p_coh[0];
    const float E     = __expf(yml);
    const float sphi  = __sinf(fa * 0.017453292519943295f);
    const float alpha = 1.632993161855452f * sphi * frcp(3.0f - sphi);
    const float mu    = E * 0.5f * frcp(1.0f + nu);
    const float la    = E * nu * frcp((1.0f + nu) * (1.0f - 2.0f * nu));
    const float ratio = (3.0f * la + 2.0f * mu) * frcp(2.0f * mu) * alpha;

    // ---- working columns + squared norms for BOTH elements (A regs not kept) ----
    float A00,A10,A20, A01,A11,A21, A02,A12,A22;   // element 0 working cols
    float B00,B10,B20, B01,B11,B21, B02,B12,B22;   // element 1 working cols
    float An0, An1, An2, Bn0, Bn1, Bn2;
    {
        const float* p = lds + off0;   // stride 9: 2-way bank alias only (free)
        A00 = p[0]; A01 = p[1]; A02 = p[2];
        A10 = p[3]; A11 = p[4]; A12 = p[5];
        A20 = p[6]; A21 = p[7]; A22 = p[8];
    }
    {
        const float* p = lds + off1;
        B00 = p[0]; B01 = p[1]; B02 = p[2];
        B10 = p[3]; B11 = p[4]; B12 = p[5];
        B20 = p[6]; B21 = p[7]; B22 = p[8];
    }
    An0 = fmaf(A00,A00, fmaf(A10,A10, A20*A20));
    An1 = fmaf(A01,A01, fmaf(A11,A11, A21*A21));
    An2 = fmaf(A02,A02, fmaf(A12,A12, A22*A22));
    Bn0 = fmaf(B00,B00, fmaf(B10,B10, B20*B20));
    Bn1 = fmaf(B01,B01, fmaf(B11,B11, B21*B21));
    Bn2 = fmaf(B02,B02, fmaf(B12,B12, B22*B22));

    // ---- one-sided Jacobi, 4 sweeps, two independent chains interleaved ----
    #pragma unroll
    for (int sweep = 0; sweep < 4; ++sweep) {
        rot(A00,A10,A20,An0, A01,A11,A21,An1);
        rot(B00,B10,B20,Bn0, B01,B11,B21,Bn1);
        rot(A00,A10,A20,An0, A02,A12,A22,An2);
        rot(B00,B10,B20,Bn0, B02,B12,B22,Bn2);
        rot(A01,A11,A21,An1, A02,A12,A22,An2);
        rot(B01,B11,B21,Bn1, B02,B12,B22,Bn2);
    }

    // ---- epilogue (per element; original A re-read from LDS, still intact) ----
    #pragma unroll
    for (int which = 0; which < 2; ++which) {
        const int off = which ? off1 : off0;
        const bool valid = which ? valid1 : valid0;
        float c00,c10,c20, c01,c11,c21, c02,c12,c22, n0,n1;
        if (which) {
            c00=B00;c10=B10;c20=B20; c01=B01;c11=B11;c21=B21; c02=B02;c12=B12;c22=B22;
            n0=Bn0; n1=Bn1;
        } else {
            c00=A00;c10=A10;c20=A20; c01=A01;c11=A11;c21=A21; c02=A02;c12=A12;c22=A22;
            n0=An0; n1=An1;
        }

        // original matrix back from LDS (thread-private slot)
        const float* p = lds + off;
        float a00=p[0], a01=p[1], a02=p[2];
        float a10=p[3], a11=p[4], a12=p[5];
        float a20=p[6], a21=p[7], a22=p[8];

        float i0 = frsq(fmaxf(n0, 1e-30f));
        float i1 = frsq(fmaxf(n1, 1e-30f));
        float u00 = c00*i0, u10 = c10*i0, u20 = c20*i0;
        float u01 = c01*i1, u11 = c11*i1, u21 = c21*i1;
        float sig0 = n0 * i0;
        float sig1 = n1 * i1;
        float u02 = fmaf(u10,u21, -u20*u11);
        float u12 = fmaf(u20,u01, -u00*u21);
        float u22 = fmaf(u00,u11, -u10*u01);

        float q0 = fmaf(a00,u00, fmaf(a10,u10, a20*u20));
        float q1 = fmaf(a01,u00, fmaf(a11,u10, a21*u20));
        float q2 = fmaf(a02,u00, fmaf(a12,u10, a22*u20));
        float m0 = fmaf(q0,q0, fmaf(q1,q1, q2*q2));
        float j0 = frsq(fmaxf(m0, 1e-30f));
        float v00 = q0*j0, v10 = q1*j0, v20 = q2*j0;

        q0 = fmaf(a00,u01, fmaf(a10,u11, a20*u21));
        q1 = fmaf(a01,u01, fmaf(a11,u11, a21*u21));
        q2 = fmaf(a02,u01, fmaf(a12,u11, a22*u21));
        float m1 = fmaf(q0,q0, fmaf(q1,q1, q2*q2));
        float j1 = frsq(fmaxf(m1, 1e-30f));
        float v01 = q0*j1, v11 = q1*j1, v21 = q2*j1;

        float v02 = fmaf(v10,v21, -v20*v11);
        float v12 = fmaf(v20,v01, -v00*v21);
        float v22 = fmaf(v00,v11, -v10*v01);

        float w0 = fmaf(a00,v02, fmaf(a01,v12, a02*v22));
        float w1 = fmaf(a10,v02, fmaf(a11,v12, a12*v22));
        float w2 = fmaf(a20,v02, fmaf(a21,v12, a22*v22));
        float s2 = fmaf(u02,w0, fmaf(u12,w1, u22*w2));
        float sig2 = fabsf(s2);

        float e0f = __logf(fmaxf(sig0, 0.05f));
        float e1f = __logf(fmaxf(sig1, 0.05f));
        float e2f = __logf(fmaxf(sig2, 0.05f));
        float tr  = e0f + e1f + e2f;
        float tr3 = tr * (1.0f / 3.0f);
        float h0 = e0f - tr3, h1 = e1f - tr3, h2 = e2f - tr3;
        float hn = sqrtf(fmaf(h0,h0, fmaf(h1,h1, h2*h2)));
        hn = fmaxf(hn, 1e-10f);
        float st = tr - coh * 3.0f;
        float dg = hn + ratio * st;
        float sc = fmaxf(dg, 0.0f) * frcp(hn);
        bool yield = st < 0.0f;
        float ec0 = yield ? fmaf(-sc, h0, e0f) : coh;
        float ec1 = yield ? fmaf(-sc, h1, e1f) : coh;
        float ec2 = yield ? fmaf(-sc, h2, e2f) : coh;
        float f0 = __expf(ec0);
        float f1 = __expf(ec1);
        float f2 = copysignf(__expf(ec2), s2);

        float w00 = u00*f0, w01 = u01*f1, w02 = u02*f2;
        float w10 = u10*f0, w11 = u11*f1, w12 = u12*f2;
        float w20 = u20*f0, w21 = u21*f1, w22 = u22*f2;
        float r00 = fmaf(w00,v00, fmaf(w01,v01, w02*v02));
        float r01 = fmaf(w00,v10, fmaf(w01,v11, w02*v12));
        float r02 = fmaf(w00,v20, fmaf(w01,v21, w02*v22));
        float r10 = fmaf(w10,v00, fmaf(w11,v01, w12*v02));
        float r11 = fmaf(w10,v10, fmaf(w11,v11, w12*v12));
        float r12 = fmaf(w10,v20, fmaf(w11,v21, w12*v22));
        float r20 = fmaf(w20,v00, fmaf(w21,v01, w22*v02));
        float r21 = fmaf(w20,v10, fmaf(w21,v11, w22*v12));
        float r22 = fmaf(w20,v20, fmaf(w21,v21, w22*v22));

        // write result into own LDS slot (only this thread ever touches it)
        if (valid) {
            float* o = lds + off;
            o[0]=r00; o[1]=r01; o[2]=r02;
            o[3]=r10; o[4]=r11; o[5]=r12;
            o[6]=r20; o[7]=r21; o[8]=r22;
        }
    }
    __syncthreads();

    // ---- stage out: coalesced float4 ----
    #pragma unroll
    for (int j = 0; j < 5; ++j) {
        int idx = t_id + j * BLOCK;
        if (idx < (EPB * 9) / 4) {
            long long g4 = base_f / 4 + idx;
            long long gf = g4 * 4;
            if (gf + 3 < nfloats) {
                ((float4*)out)[g4] = ((float4*)lds)[idx];
            } else {
                #pragma unroll
                for (int k = 0; k < 4; ++k)
                    if (gf + k < nfloats) out[gf + k] = lds[idx * 4 + k];
            }
        }
    }
}

extern "C" void kernel_launch(void* const* d_in, const int* in_sizes, int n_in,
                              void* d_out, int out_size, void* d_ws, size_t ws_size,
                              hipStream_t stream) {
    const float* F = (const float*)d_in[0];
    const int n_elem = in_sizes[0] / 9;
    const int grid = (n_elem + EPB - 1) / EPB;
    dp_kernel<<<grid, BLOCK, 0, stream>>>(
        F,
        (const float*)d_in[1], (const float*)d_in[2],
        (const float*)d_in[3], (const float*)d_in[4],
        (float*)d_out, n_elem);
}